// Round 10
// baseline (423.040 us; speedup 1.0000x reference)
//
#include <hip/hip_runtime.h>
#include <math.h>

#define NN   100000
#define EE   1600000
#define ET   (EE + NN)          // edges + self-loops = 1,700,000
#define HID  64
#define MLPH 128
#define ODIM 74
#define SLOPE 0.2f

#define NB   196                // coarse buckets of 512 nodes (dst >> 9)
#define GA   800                // pass-A blocks
#define EPB  (EE / GA)          // 2000 edges per pass-A block

__device__ __forceinline__ float f4get(const float4& v, int i) {
    return i == 0 ? v.x : i == 1 ? v.y : i == 2 ? v.z : v.w;  // unrolled -> constant
}

// ================= CSR build: bucketed counting sort, no global atomics =================

__global__ void k_partA_hist(const int* __restrict__ edst, int* __restrict__ M) {
    __shared__ int hist[NB];
    int t = threadIdx.x;
    if (t < NB) hist[t] = 0;
    __syncthreads();
    int base = blockIdx.x * EPB;
    for (int i = t; i < EPB; i += 256)
        atomicAdd(&hist[edst[base + i] >> 9], 1);
    __syncthreads();
    if (t < NB) M[blockIdx.x * NB + t] = hist[t];
}

__global__ void k_scan_col(const int* __restrict__ M, int* __restrict__ colExcl,
                           int* __restrict__ colsum) {
    __shared__ int sd[256];
    __shared__ int carry;
    int k = blockIdx.x, t = threadIdx.x;
    if (t == 0) carry = 0;
    __syncthreads();
    for (int c = 0; c < GA; c += 256) {
        int v = (c + t < GA) ? M[(c + t) * NB + k] : 0;
        sd[t] = v;
        __syncthreads();
        for (int o = 1; o < 256; o <<= 1) {
            int u = (t >= o) ? sd[t - o] : 0;
            __syncthreads();
            sd[t] += u;
            __syncthreads();
        }
        if (c + t < GA) colExcl[(c + t) * NB + k] = carry + sd[t] - v;
        __syncthreads();
        if (t == 255) carry += sd[255];
        __syncthreads();
    }
    if (t == 0) colsum[k] = carry;
}

__global__ void k_scan_bkt(const int* __restrict__ colsum, int* __restrict__ bucketBase) {
    __shared__ int sd[256];
    int t = threadIdx.x;
    int v = (t < NB) ? colsum[t] : 0;
    sd[t] = v;
    __syncthreads();
    for (int o = 1; o < 256; o <<= 1) {
        int u = (t >= o) ? sd[t - o] : 0;
        __syncthreads();
        sd[t] += u;
        __syncthreads();
    }
    if (t < NB) bucketBase[t] = sd[t] - v;
    if (t == NB - 1) bucketBase[NB] = sd[t];
}

__global__ void k_partA_scat(const int* __restrict__ esrc, const int* __restrict__ edst,
                             const int* __restrict__ colExcl, const int* __restrict__ bucketBase,
                             unsigned long long* __restrict__ tmp) {
    __shared__ int cur[NB];
    int t = threadIdx.x;
    if (t < NB) cur[t] = bucketBase[t] + colExcl[blockIdx.x * NB + t];
    __syncthreads();
    int base = blockIdx.x * EPB;
    for (int i = t; i < EPB; i += 256) {
        int s = esrc[base + i], d = edst[base + i];
        int pos = atomicAdd(&cur[d >> 9], 1);
        tmp[pos] = ((unsigned long long)(unsigned)d << 32) | (unsigned)s;
    }
}

__global__ __launch_bounds__(512) void k_partB(
        const unsigned long long* __restrict__ tmp, const int* __restrict__ bucketBase,
        int* __restrict__ rowbeg, int* __restrict__ rowend, int* __restrict__ col) {
    __shared__ int deg[512];
    __shared__ int rb[512];
    __shared__ int cur[512];
    int k = blockIdx.x, t = threadIdx.x;
    int lo = bucketBase[k], hi = bucketBase[k + 1];
    int nodeBase = k << 9;
    int nNodes = (NN - nodeBase < 512) ? (NN - nodeBase) : 512;

    deg[t] = 0;
    __syncthreads();
    for (int i = lo + t; i < hi; i += 512)
        atomicAdd(&deg[(int)(tmp[i] >> 32) - nodeBase], 1);
    __syncthreads();

    int v = (t < nNodes) ? deg[t] + 1 : 0;
    rb[t] = v;
    __syncthreads();
    for (int o = 1; o < 512; o <<= 1) {
        int u = (t >= o) ? rb[t - o] : 0;
        __syncthreads();
        rb[t] += u;
        __syncthreads();
    }
    int myBeg = lo + nodeBase + rb[t] - v;
    if (t < nNodes) {
        int g = nodeBase + t;
        rowbeg[g] = myBeg;
        rowend[g] = myBeg + deg[t] + 1;
        col[myBeg] = g;              // self-loop first in row
        cur[t] = myBeg + 1;
    }
    __syncthreads();
    for (int i = lo + t; i < hi; i += 512) {
        unsigned long long e = tmp[i];
        int dLow = (int)(e >> 32) - nodeBase;
        int pos = atomicAdd(&cur[dLow], 1);
        col[pos] = (int)(e & 0xffffffffu);
    }
}

// ---------------- dense prologues ----------------

__global__ void k_lin1(const float* __restrict__ x, const float* __restrict__ W,
                       const float* __restrict__ asrc, const float* __restrict__ adst,
                       float* __restrict__ h, float* __restrict__ hs, float* __restrict__ hd) {
    int node = blockIdx.x * 4 + (threadIdx.x >> 6);
    int f    = threadIdx.x & 63;
    float x0 = x[node*3+0], x1 = x[node*3+1], x2 = x[node*3+2];
    float v  = x0*W[f] + x1*W[64+f] + x2*W[128+f];
    h[node*64+f] = v;
    float ps = v*asrc[f], pd = v*adst[f];
    #pragma unroll
    for (int o = 32; o > 0; o >>= 1) { ps += __shfl_down(ps, o); pd += __shfl_down(pd, o); }
    if (f == 0) { hs[node] = ps; hd[node] = pd; }
}

__global__ __launch_bounds__(128) void k_lin64(
        const float* __restrict__ xin, const float* __restrict__ W,
        const float* __restrict__ asrc, const float* __restrict__ adst,
        float* __restrict__ h, float* __restrict__ hs, float* __restrict__ hd) {
    __shared__ __align__(16) float xr[32][64];     // 8 KB (x rows, later reused for h rows)
    __shared__ __align__(16) float wl[64*64];      // 16 KB, [k][o] layout
    int t  = threadIdx.x;
    int nb = blockIdx.x * 32;
    for (int i = t; i < 32*64; i += 128) xr[i >> 6][i & 63] = xin[nb*64 + i];
    for (int i = t; i < 64*64;  i += 128) wl[i] = W[i];
    __syncthreads();

    int nq = t >> 4;    // 0..7 (4 nodes each)
    int hq = t & 15;    // 0..15 (4 outs each)
    float acc[4][4] = {};
    #pragma unroll 4
    for (int k = 0; k < 64; k += 4) {
        float4 xv[4];
        #pragma unroll
        for (int ni = 0; ni < 4; ++ni) xv[ni] = *(const float4*)&xr[nq*4+ni][k];
        #pragma unroll
        for (int kk = 0; kk < 4; ++kk) {
            float4 wv = *(const float4*)&wl[(k+kk)*64 + hq*4];
            #pragma unroll
            for (int ni = 0; ni < 4; ++ni) {
                float xs = f4get(xv[ni], kk);
                acc[ni][0] += xs*wv.x; acc[ni][1] += xs*wv.y;
                acc[ni][2] += xs*wv.z; acc[ni][3] += xs*wv.w;
            }
        }
    }
    float4 res[4];
    #pragma unroll
    for (int ni = 0; ni < 4; ++ni) {
        res[ni] = make_float4(acc[ni][0], acc[ni][1], acc[ni][2], acc[ni][3]);
        *(float4*)&h[(size_t)(nb + nq*4 + ni)*64 + hq*4] = res[ni];
    }
    __syncthreads();
    #pragma unroll
    for (int ni = 0; ni < 4; ++ni) *(float4*)&xr[nq*4+ni][hq*4] = res[ni];
    __syncthreads();

    int wv_  = t >> 6;
    int lane = t & 63;
    for (int ni = 0; ni < 16; ++ni) {
        int node = wv_*16 + ni;
        float v  = xr[node][lane];
        float ps = v*asrc[lane], pd = v*adst[lane];
        #pragma unroll
        for (int o = 32; o > 0; o >>= 1) { ps += __shfl_down(ps, o); pd += __shfl_down(pd, o); }
        if (lane == 0) { hs[nb+node] = ps; hd[nb+node] = pd; }
    }
}

// ---------------- fused GAT aggregate v2: float4 group-gather in phase B ----------------
// One wave per dst node. Phase B: lane = (g = edge subgroup 0..3, q = f4 slot 0..15);
// one global_load_dwordx4 covers 4 source rows; unroll x2 -> 8 loads in flight.
__global__ void k_gat(const int* __restrict__ rowbeg, const int* __restrict__ rowend,
                      const int* __restrict__ col,
                      const float* __restrict__ hs, const float* __restrict__ hd,
                      const float* __restrict__ h, const float* __restrict__ bias,
                      float* __restrict__ out) {
    __shared__ float se[4][128];
    __shared__ int   sc[4][128];
    int w    = threadIdx.x >> 6;
    int lane = threadIdx.x & 63;
    int n    = blockIdx.x * 4 + w;
    float* e_ = se[w];
    int*   c_ = sc[w];

    int base = rowbeg[n];
    int d    = rowend[n] - base;          // >=1 (self-loop)
    float hdn = hd[n];

    // phase A1: scores (+ stash col) + wave max
    float mymax = -INFINITY;
    for (int k = lane; k < d; k += 64) {
        int s = col[base + k];
        float scv = hs[s] + hdn;
        scv = (scv > 0.f) ? scv : SLOPE * scv;
        if (k < 128) { e_[k] = scv; c_[k] = s; }
        mymax = fmaxf(mymax, scv);
    }
    #pragma unroll
    for (int o = 32; o > 0; o >>= 1) mymax = fmaxf(mymax, __shfl_xor(mymax, o));

    // phase A2: exp + wave sum
    float mysum = 0.f;
    for (int k = lane; k < d; k += 64) {
        float scv;
        if (k < 128) scv = e_[k];
        else {
            int s = col[base + k];
            scv = hs[s] + hdn;
            scv = (scv > 0.f) ? scv : SLOPE * scv;
        }
        float p = expf(scv - mymax);
        if (k < 128) e_[k] = p;
        mysum += p;
    }
    #pragma unroll
    for (int o = 32; o > 0; o >>= 1) mysum += __shfl_xor(mysum, o);
    float inv = 1.f / mysum;

    __syncthreads();   // publish p/col for cross-lane reads

    // phase B: 4 edges at a time via float4 lanes, x2 unroll
    int g = lane >> 4;        // edge subgroup
    int q = lane & 15;        // float4 slot (features q*4..q*4+3)
    int dl = (d < 128) ? d : 128;
    float4 acc4 = make_float4(0.f, 0.f, 0.f, 0.f);
    int k = g;
    for (; k + 4 < dl; k += 8) {
        float p0 = e_[k];     int s0 = c_[k];
        float p1 = e_[k+4];   int s1 = c_[k+4];
        float4 h0 = *(const float4*)&h[(size_t)s0*64 + q*4];
        float4 h1 = *(const float4*)&h[(size_t)s1*64 + q*4];
        acc4.x += p0*h0.x + p1*h1.x;
        acc4.y += p0*h0.y + p1*h1.y;
        acc4.z += p0*h0.z + p1*h1.z;
        acc4.w += p0*h0.w + p1*h1.w;
    }
    if (k < dl) {
        float p0 = e_[k];     int s0 = c_[k];
        float4 h0 = *(const float4*)&h[(size_t)s0*64 + q*4];
        acc4.x += p0*h0.x; acc4.y += p0*h0.y; acc4.z += p0*h0.z; acc4.w += p0*h0.w;
    }
    for (int kk = 128 + g; kk < d; kk += 4) {   // d>128 spill path (never hit at E[deg]=17)
        int s = col[base + kk];
        float scv = hs[s] + hdn;
        scv = (scv > 0.f) ? scv : SLOPE * scv;
        float p = expf(scv - mymax);
        float4 hv = *(const float4*)&h[(size_t)s*64 + q*4];
        acc4.x += p*hv.x; acc4.y += p*hv.y; acc4.z += p*hv.z; acc4.w += p*hv.w;
    }
    // reduce across the 4 edge subgroups (lanes q, q+16, q+32, q+48)
    #pragma unroll
    for (int o = 16; o <= 32; o <<= 1) {
        acc4.x += __shfl_xor(acc4.x, o);
        acc4.y += __shfl_xor(acc4.y, o);
        acc4.z += __shfl_xor(acc4.z, o);
        acc4.w += __shfl_xor(acc4.w, o);
    }
    if (g == 0) {
        float4 bv = *(const float4*)&bias[q*4];
        float4 r;
        r.x = fmaxf(acc4.x*inv + bv.x, 0.f);
        r.y = fmaxf(acc4.y*inv + bv.y, 0.f);
        r.z = fmaxf(acc4.z*inv + bv.z, 0.f);
        r.w = fmaxf(acc4.w*inv + bv.w, 0.f);
        *(float4*)&out[(size_t)n*64 + q*4] = r;
    }
}

// ---------------- MLP head v6: software-pipelined weight prefetch ----------------
// v5 lesson: f4 LDS reads alone didn't move (88us ~= 86us scalar) -> stall is global
// weight-load latency. Fix: double-buffer weights in registers, #pragma unroll 1.
__global__ __launch_bounds__(256) void k_mlp(
        const float* __restrict__ xin,
        const float* __restrict__ Wp1, const float* __restrict__ bp1,
        const float* __restrict__ Wp2, const float* __restrict__ bp2,
        float* __restrict__ out) {
    __shared__ __align__(16) float xr[32][64];     // 8 KB
    __shared__ __align__(16) float hid[32][132];   // 16.9 KB; stride 132 = 33x16B
    int t  = threadIdx.x;
    int nb = blockIdx.x * 32;
    int nq = t >> 5;      // 0..7  (4 nodes each)
    int hq = t & 31;      // 0..31

    for (int i = t; i < 32*64; i += 256) xr[i >> 6][i & 63] = xin[(size_t)nb*64 + i];
    __syncthreads();

    // phase 1: hid = relu(x @ Wp1 + bp1)
    {
        float4 bv = *(const float4*)&bp1[hq*4];
        float acc[4][4];
        #pragma unroll
        for (int ni = 0; ni < 4; ++ni) {
            acc[ni][0] = bv.x; acc[ni][1] = bv.y; acc[ni][2] = bv.z; acc[ni][3] = bv.w;
        }
        const float* wp = &Wp1[hq*4];
        float4 wc[4], wn[4];
        #pragma unroll
        for (int kk = 0; kk < 4; ++kk) wc[kk] = *(const float4*)&wp[kk*MLPH];
        #pragma unroll 1
        for (int k = 0; k < 64; k += 4) {
            if (k + 4 < 64) {
                #pragma unroll
                for (int kk = 0; kk < 4; ++kk) wn[kk] = *(const float4*)&wp[(k+4+kk)*MLPH];
            }
            float4 xv[4];
            #pragma unroll
            for (int ni = 0; ni < 4; ++ni) xv[ni] = *(const float4*)&xr[nq*4+ni][k];
            #pragma unroll
            for (int kk = 0; kk < 4; ++kk) {
                #pragma unroll
                for (int ni = 0; ni < 4; ++ni) {
                    float xs = f4get(xv[ni], kk);
                    acc[ni][0] += xs*wc[kk].x; acc[ni][1] += xs*wc[kk].y;
                    acc[ni][2] += xs*wc[kk].z; acc[ni][3] += xs*wc[kk].w;
                }
            }
            #pragma unroll
            for (int kk = 0; kk < 4; ++kk) wc[kk] = wn[kk];
        }
        #pragma unroll
        for (int ni = 0; ni < 4; ++ni)
            *(float4*)&hid[nq*4+ni][hq*4] = make_float4(
                fmaxf(acc[ni][0], 0.f), fmaxf(acc[ni][1], 0.f),
                fmaxf(acc[ni][2], 0.f), fmaxf(acc[ni][3], 0.f));
    }
    __syncthreads();

    // phase 2: out = hid @ Wp2 + bp2
    {
        int oq = t & 31;
        bool has3 = (oq + 64) < ODIM;   // oq < 10
        float a0[4], a1[4], a2[4];
        float b0 = bp2[oq], b1v = bp2[oq+32], b2v = has3 ? bp2[oq+64] : 0.f;
        #pragma unroll
        for (int ni = 0; ni < 4; ++ni) { a0[ni] = b0; a1[ni] = b1v; a2[ni] = b2v; }
        float wc0[4], wc1[4], wc2[4], wn0[4], wn1[4], wn2[4];
        #pragma unroll
        for (int jj = 0; jj < 4; ++jj) {
            wc0[jj] = Wp2[jj*ODIM + oq];
            wc1[jj] = Wp2[jj*ODIM + oq + 32];
            wc2[jj] = has3 ? Wp2[jj*ODIM + oq + 64] : 0.f;
        }
        #pragma unroll 1
        for (int j = 0; j < MLPH; j += 4) {
            if (j + 4 < MLPH) {
                #pragma unroll
                for (int jj = 0; jj < 4; ++jj) {
                    wn0[jj] = Wp2[(j+4+jj)*ODIM + oq];
                    wn1[jj] = Wp2[(j+4+jj)*ODIM + oq + 32];
                    wn2[jj] = has3 ? Wp2[(j+4+jj)*ODIM + oq + 64] : 0.f;
                }
            }
            float4 hv[4];
            #pragma unroll
            for (int ni = 0; ni < 4; ++ni) hv[ni] = *(const float4*)&hid[nq*4+ni][j];
            #pragma unroll
            for (int jj = 0; jj < 4; ++jj) {
                float h0 = f4get(hv[0], jj), h1 = f4get(hv[1], jj);
                float h2 = f4get(hv[2], jj), h3 = f4get(hv[3], jj);
                a0[0] += h0*wc0[jj]; a1[0] += h0*wc1[jj]; a2[0] += h0*wc2[jj];
                a0[1] += h1*wc0[jj]; a1[1] += h1*wc1[jj]; a2[1] += h1*wc2[jj];
                a0[2] += h2*wc0[jj]; a1[2] += h2*wc1[jj]; a2[2] += h2*wc2[jj];
                a0[3] += h3*wc0[jj]; a1[3] += h3*wc1[jj]; a2[3] += h3*wc2[jj];
            }
            #pragma unroll
            for (int jj = 0; jj < 4; ++jj) { wc0[jj] = wn0[jj]; wc1[jj] = wn1[jj]; wc2[jj] = wn2[jj]; }
        }
        #pragma unroll
        for (int ni = 0; ni < 4; ++ni) {
            size_t rowo = (size_t)(nb + nq*4 + ni) * ODIM;
            out[rowo + oq]      = a0[ni];
            out[rowo + oq + 32] = a1[ni];
            if (has3) out[rowo + oq + 64] = a2[ni];
        }
    }
}

// ---------------- launch ----------------

extern "C" void kernel_launch(void* const* d_in, const int* in_sizes, int n_in,
                              void* d_out, int out_size, void* d_ws, size_t ws_size,
                              hipStream_t stream) {
    const float* x    = (const float*)d_in[0];
    const int*   ei   = (const int*)  d_in[1];
    const float* W1   = (const float*)d_in[2];
    const float* a1s  = (const float*)d_in[3];
    const float* a1d  = (const float*)d_in[4];
    const float* b1   = (const float*)d_in[5];
    const float* W2   = (const float*)d_in[6];
    const float* a2s  = (const float*)d_in[7];
    const float* a2d  = (const float*)d_in[8];
    const float* b2   = (const float*)d_in[9];
    const float* Wp1  = (const float*)d_in[10];
    const float* bp1  = (const float*)d_in[11];
    const float* Wp2  = (const float*)d_in[12];
    const float* bp2  = (const float*)d_in[13];
    float* out = (float*)d_out;

    const int* esrc = ei;
    const int* edst = ei + EE;

    float* ws   = (float*)d_ws;
    float* bufA = ws;                      // h (N*64); first 12.8MB overlaid by tmp during CSR build
    float* bufB = bufA + NN*HID;           // layer outputs (N*64)
    float* hs   = bufB + NN*HID;           // N
    float* hd   = hs + NN;                 // N
    int* rowbeg = (int*)(hd + NN);         // N
    int* rowend = rowbeg + NN;             // N
    int* col    = rowend + NN;             // ET
    int* M      = col + ET;                // GA*NB
    int* colExcl= M + GA*NB;               // GA*NB
    int* colsum = colExcl + GA*NB;         // NB
    int* bucketBase = colsum + NB;         // NB+1
    unsigned long long* tmp = (unsigned long long*)bufA;   // EE packed records (12.8MB)

    // ---- CSR build (no global atomics; shared by both layers) ----
    k_partA_hist<<<GA, 256, 0, stream>>>(edst, M);
    k_scan_col  <<<NB, 256, 0, stream>>>(M, colExcl, colsum);
    k_scan_bkt  <<<1, 256, 0, stream>>>(colsum, bucketBase);
    k_partA_scat<<<GA, 256, 0, stream>>>(esrc, edst, colExcl, bucketBase, tmp);
    k_partB     <<<NB, 512, 0, stream>>>(tmp, bucketBase, rowbeg, rowend, col);

    // ---- GAT layer 1 (k_lin1 writes bufA after tmp is consumed; stream-ordered) ----
    k_lin1<<<NN/4, 256, 0, stream>>>(x, W1, a1s, a1d, bufA, hs, hd);
    k_gat <<<NN/4, 256, 0, stream>>>(rowbeg, rowend, col, hs, hd, bufA, b1, bufB);

    // ---- GAT layer 2 ----
    k_lin64<<<NN/32, 128, 0, stream>>>(bufB, W2, a2s, a2d, bufA, hs, hd);
    k_gat  <<<NN/4, 256, 0, stream>>>(rowbeg, rowend, col, hs, hd, bufA, b2, bufB);

    // ---- MLP head ----
    k_mlp<<<NN/32, 256, 0, stream>>>(bufB, Wp1, bp1, Wp2, bp2, out);
}